// Round 1
// baseline (82.271 us; speedup 1.0000x reference)
//
#include <hip/hip_runtime.h>

#define EPSF 1e-20f

constexpr int Hh = 768, Ww = 768, Bb = 4;
constexpr int PLANE = Hh * Ww;
constexpr int TS = 32;        // output tile
constexpr int ET = TS + 2;    // halo-1 region (t planes / s plane)
constexpr int LT = TS + 4;    // halo-2 region (dcd/cd for stage 1)

// ---- weight preparation (softplus/sigmoid + normalization), 1 thread ----
__global__ __launch_bounds__(64)
void prep_weights(const float* __restrict__ wsd_in, const float* __restrict__ wpow_in,
                  const float* __restrict__ wprop_in, const float* __restrict__ wss_in,
                  float* __restrict__ wbuf) {
    if (threadIdx.x != 0) return;
    float sd[9], ss[9];
    float sum_d = 0.f, sum_s = 0.f;
    for (int r = 0; r < 3; ++r) {
        for (int c = 0; c < 3; ++c) {
            int cc = (c == 2) ? 0 : c;              // mirrored 3rd column
            float vd = log1pf(expf(wsd_in[r * 2 + cc]));
            float vs = log1pf(expf(wss_in[r * 2 + cc]));
            sd[r * 3 + c] = vd; ss[r * 3 + c] = vs;
            sum_d += vd; sum_s += vs;
        }
    }
    for (int k = 0; k < 9; ++k) { wbuf[k] = sd[k] / sum_d; wbuf[9 + k] = ss[k] / sum_s; }
    wbuf[18] = 1.f / (1.f + expf(-wprop_in[0]));    // wps (sigmoid)
    wbuf[19] = log1pf(expf(wpow_in[0]));            // wpow (softplus)
}

// ---- K1: stage 1 (argmax/gather/pow/blend) + stage 2 (3x3 conv) ----
__global__ __launch_bounds__(256)
void k1_stage12(const float* __restrict__ x, const float* __restrict__ scs,
                const float* __restrict__ cs, const float* __restrict__ wbuf,
                float* __restrict__ out) {
    __shared__ float s_d[LT][LT + 1];
    __shared__ float s_c[LT][LT + 1];
    __shared__ float s_tc[ET][ET + 1];
    __shared__ float s_ts[ET][ET + 1];
    const int b = blockIdx.z;
    const int ty0 = blockIdx.y * TS, tx0 = blockIdx.x * TS;
    const int tid = threadIdx.x;
    const float* dcd = x + b * PLANE;
    const float* cd  = x + (Bb + b) * PLANE;

    // load dcd/cd at halo 2 (zeros outside image)
    for (int i = tid; i < LT * LT; i += 256) {
        int ly = i / LT, lx = i - ly * LT;
        int gy = ty0 - 2 + ly, gx = tx0 - 2 + lx;
        float vd = 0.f, vc = 0.f;
        if ((unsigned)gy < (unsigned)Hh && (unsigned)gx < (unsigned)Ww) {
            vd = dcd[gy * Ww + gx];
            vc = cd[gy * Ww + gx];
        }
        s_d[ly][lx] = vd; s_c[ly][lx] = vc;
    }
    __syncthreads();

    const float wps  = wbuf[18];
    const float wpow = wbuf[19];

    // stage 1 on halo-1 region; zeros outside image (conv zero-pad)
    for (int i = tid; i < ET * ET; i += 256) {
        int ly = i / ET, lx = i - ly * ET;
        int gy = ty0 - 1 + ly, gx = tx0 - 1 + lx;
        float tc = 0.f, ts = 0.f;
        if ((unsigned)gy < (unsigned)Hh && (unsigned)gx < (unsigned)Ww) {
            float amax = -INFINITY, bmax = -INFINITY;
            float d_jmax = 0.f, d_jmin = 0.f, c_jmax = 0.f, c_jmin = 0.f;
            #pragma unroll
            for (int k = 0; k < 9; ++k) {
                float vd = s_d[ly + k / 3][lx + k % 3];
                float vc = s_c[ly + k / 3][lx + k % 3];
                float dq = vd / (vc + EPSF);   // d=0 outside image (vd=vc=0)
                float aq = dq * vc;
                float bq = vc / (dq + EPSF);
                if (aq > amax) { amax = aq; d_jmax = dq; c_jmax = vc; }  // first-max wins
                if (bq > bmax) { bmax = bq; d_jmin = dq; c_jmin = vc; }
            }
            float s_new  = powf((d_jmin + EPSF) / (d_jmax + EPSF), wpow);
            float cs_new = c_jmax * c_jmin;
            int idx = gy * Ww + gx;
            float csv  = cs[b * PLANE + idx];
            float scsv = scs[b * PLANE + idx];
            tc = csv * wps + cs_new * (1.f - wps);
            ts = scsv * wps + s_new * cs_new * (1.f - wps);
        }
        s_tc[ly][lx] = tc; s_ts[ly][lx] = ts;
    }
    __syncthreads();

    float wk[9];
    #pragma unroll
    for (int k = 0; k < 9; ++k) wk[k] = wbuf[9 + k];

    // stage 2: 3x3 conv -> scs_out (planes 8..11), cs_out (planes 12..15)
    for (int i = tid; i < TS * TS; i += 256) {
        int ly = i / TS, lx = i - ly * TS;
        int gy = ty0 + ly, gx = tx0 + lx;   // H,W divisible by TS
        float accC = 0.f, accS = 0.f;
        #pragma unroll
        for (int k = 0; k < 9; ++k) {
            accC += wk[k] * s_tc[ly + k / 3][lx + k % 3];
            accS += wk[k] * s_ts[ly + k / 3][lx + k % 3];
        }
        int idx = gy * Ww + gx;
        out[(8 + b)  * PLANE + idx] = accS;
        out[(12 + b) * PLANE + idx] = accC;
    }
}

// ---- K2: stage 3 (s-weighted 9-tap normalization -> x_out) ----
__global__ __launch_bounds__(256)
void k2_stage3(const float* __restrict__ x, const float* __restrict__ wbuf,
               float* __restrict__ out) {
    __shared__ float s_s[ET][ET + 1];
    __shared__ float s_d[ET][ET + 1];
    __shared__ float s_c[ET][ET + 1];
    const int b = blockIdx.z;
    const int ty0 = blockIdx.y * TS, tx0 = blockIdx.x * TS;
    const int tid = threadIdx.x;
    const float* dcd   = x + b * PLANE;
    const float* cd    = x + (Bb + b) * PLANE;
    const float* scs_o = out + (8 + b)  * PLANE;
    const float* cs_o  = out + (12 + b) * PLANE;

    for (int i = tid; i < ET * ET; i += 256) {
        int ly = i / ET, lx = i - ly * ET;
        int gy = ty0 - 1 + ly, gx = tx0 - 1 + lx;
        float sv = 0.f, vd = 0.f, vc = 0.f;
        if ((unsigned)gy < (unsigned)Hh && (unsigned)gx < (unsigned)Ww) {
            int idx = gy * Ww + gx;
            sv = scs_o[idx] / (cs_o[idx] + EPSF);
            vd = dcd[idx];
            vc = cd[idx];
        }
        s_s[ly][lx] = sv; s_d[ly][lx] = vd; s_c[ly][lx] = vc;
    }
    __syncthreads();

    float wd[9];
    #pragma unroll
    for (int k = 0; k < 9; ++k) wd[k] = wbuf[k];

    for (int i = tid; i < TS * TS; i += 256) {
        int ly = i / TS, lx = i - ly * TS;
        int gy = ty0 + ly, gx = tx0 + lx;
        float sc = s_s[ly + 1][lx + 1];
        float nd = 0.f, nc = 0.f, den = 0.f;
        #pragma unroll
        for (int k = 0; k < 9; ++k) {
            float wsk = (k == 4) ? 1.f : (s_s[ly + k / 3][lx + k % 3] * sc);
            float w = wd[k] * wsk;
            nd  += w * s_d[ly + k / 3][lx + k % 3];
            nc  += w * s_c[ly + k / 3][lx + k % 3];
            den += w;
        }
        den += EPSF;
        int idx = gy * Ww + gx;
        out[(2 * b)     * PLANE + idx] = nd / den;   // x_out d-part (plane 2b)
        out[(2 * b + 1) * PLANE + idx] = nc / den;   // x_out c-part (plane 2b+1)
    }
}

extern "C" void kernel_launch(void* const* d_in, const int* in_sizes, int n_in,
                              void* d_out, int out_size, void* d_ws, size_t ws_size,
                              hipStream_t stream) {
    const float* x        = (const float*)d_in[0];
    const float* scs      = (const float*)d_in[1];
    const float* cs       = (const float*)d_in[2];
    // d_in[3] = w_channel_d (1,1) -> normalizes to 1, unused
    const float* w_sp_d   = (const float*)d_in[4];
    const float* w_pow_s  = (const float*)d_in[5];
    const float* w_prop_s = (const float*)d_in[6];
    // d_in[7] = w_channel_s (1,1) -> normalizes to 1, unused
    const float* w_sp_s   = (const float*)d_in[8];
    float* out  = (float*)d_out;
    float* wbuf = (float*)d_ws;   // 20 floats

    prep_weights<<<1, 64, 0, stream>>>(w_sp_d, w_pow_s, w_prop_s, w_sp_s, wbuf);

    dim3 grid(Ww / TS, Hh / TS, Bb);   // 24 x 24 x 4
    k1_stage12<<<grid, 256, 0, stream>>>(x, scs, cs, wbuf, out);
    k2_stage3<<<grid, 256, 0, stream>>>(x, wbuf, out);
}

// Round 2
// 53.033 us; speedup vs baseline: 1.5513x; 1.5513x over previous
//
#include <hip/hip_runtime.h>

#define EPSF 1e-20f

constexpr int Hh = 768, Ww = 768, Bb = 4;
constexpr int PLANE = Hh * Ww;
constexpr int TS = 32;        // output tile
constexpr int ET = TS + 2;    // halo-1 region (t planes / s plane)
constexpr int LT = TS + 4;    // halo-2 region (dq/cd for stage 1)

// ---- K1: stage 1 (argmax/gather/pow/blend) + stage 2 (3x3 conv) ----
__global__ __launch_bounds__(256)
void k1_stage12(const float* __restrict__ x, const float* __restrict__ scs,
                const float* __restrict__ cs,
                const float* __restrict__ w_sp_s, const float* __restrict__ w_pow_s,
                const float* __restrict__ w_prop_s,
                float* __restrict__ out) {
    __shared__ float s_q[LT][LT + 1];   // dq = d/(c+eps), precise
    __shared__ float s_c[LT][LT + 1];
    __shared__ float s_tc[ET][ET + 1];
    __shared__ float s_ts[ET][ET + 1];
    __shared__ float sw[11];            // ws[0..8], wps, wpow
    const int b = blockIdx.z;
    const int ty0 = blockIdx.y * TS, tx0 = blockIdx.x * TS;
    const int tid = threadIdx.x;
    const float* dcd = x + b * PLANE;
    const float* cd  = x + (Bb + b) * PLANE;

    if (tid == 0) {   // inline weight prep (spatial_s softplus-norm, sigmoid, softplus)
        float ss[9]; float sum = 0.f;
        for (int r = 0; r < 3; ++r)
            for (int c = 0; c < 3; ++c) {
                int cc = (c == 2) ? 0 : c;
                float v = log1pf(expf(w_sp_s[r * 2 + cc]));
                ss[r * 3 + c] = v; sum += v;
            }
        for (int k = 0; k < 9; ++k) sw[k] = ss[k] / sum;
        sw[9]  = 1.f / (1.f + expf(-w_prop_s[0]));
        sw[10] = log1pf(expf(w_pow_s[0]));
    }

    // load dq/cd at halo 2 (zeros outside image); dq precise-divided once here
    for (int i = tid; i < LT * LT; i += 256) {
        int ly = i / LT, lx = i - ly * LT;
        int gy = ty0 - 2 + ly, gx = tx0 - 2 + lx;
        float vd = 0.f, vc = 0.f;
        if ((unsigned)gy < (unsigned)Hh && (unsigned)gx < (unsigned)Ww) {
            vd = dcd[gy * Ww + gx];
            vc = cd[gy * Ww + gx];
        }
        s_q[ly][lx] = vd / (vc + EPSF);
        s_c[ly][lx] = vc;
    }
    __syncthreads();

    const float wps  = sw[9];
    const float wpow = sw[10];

    // stage 1 on halo-1 region; zeros outside image (conv zero-pad)
    for (int i = tid; i < ET * ET; i += 256) {
        int ly = i / ET, lx = i - ly * ET;
        int gy = ty0 - 1 + ly, gx = tx0 - 1 + lx;
        float tc = 0.f, ts = 0.f;
        if ((unsigned)gy < (unsigned)Hh && (unsigned)gx < (unsigned)Ww) {
            // k = 0 init (first-occurrence argmax semantics)
            float dq0 = s_q[ly][lx], vc0 = s_c[ly][lx];
            float amax = dq0 * vc0;          // dp*cp
            float dmax = dq0, cmax = vc0;    // gathered at j_max
            float dqeB = dq0 + EPSF;         // (d_jmin + eps), tracked
            float vcB  = vc0;                // cd_jmin, tracked
            #pragma unroll
            for (int k = 1; k < 9; ++k) {
                float dq = s_q[ly + k / 3][lx + k % 3];
                float vc = s_c[ly + k / 3][lx + k % 3];
                float aq = dq * vc;
                bool m1 = aq > amax;
                amax = m1 ? aq : amax;
                dmax = m1 ? dq : dmax;
                cmax = m1 ? vc : cmax;
                float dqe = dq + EPSF;
                // vc/dqe > vcB/dqeB  <=>  vc*dqeB > vcB*dqe  (both denoms > 0)
                bool m2 = (vc * dqeB) > (vcB * dqe);
                dqeB = m2 ? dqe : dqeB;
                vcB  = m2 ? vc  : vcB;
            }
            // s_new = ((d_jmin+eps)/(d_jmax+eps))^wpow via hw log2/exp2
            float s_new = __builtin_amdgcn_exp2f(
                wpow * (__builtin_amdgcn_logf(dqeB) - __builtin_amdgcn_logf(dmax + EPSF)));
            float cs_new = cmax * vcB;
            int idx = gy * Ww + gx;
            float csv  = cs[b * PLANE + idx];
            float scsv = scs[b * PLANE + idx];
            tc = csv * wps + cs_new * (1.f - wps);
            ts = scsv * wps + s_new * cs_new * (1.f - wps);
        }
        s_tc[ly][lx] = tc; s_ts[ly][lx] = ts;
    }
    __syncthreads();

    float wk[9];
    #pragma unroll
    for (int k = 0; k < 9; ++k) wk[k] = sw[k];

    // stage 2: 3x3 conv -> scs_out (planes 8..11), cs_out (planes 12..15)
    for (int i = tid; i < TS * TS; i += 256) {
        int ly = i / TS, lx = i - ly * TS;
        int gy = ty0 + ly, gx = tx0 + lx;
        float accC = 0.f, accS = 0.f;
        #pragma unroll
        for (int k = 0; k < 9; ++k) {
            accC += wk[k] * s_tc[ly + k / 3][lx + k % 3];
            accS += wk[k] * s_ts[ly + k / 3][lx + k % 3];
        }
        int idx = gy * Ww + gx;
        out[(8 + b)  * PLANE + idx] = accS;
        out[(12 + b) * PLANE + idx] = accC;
    }
}

// ---- K2: stage 3 (s-weighted 9-tap normalization -> x_out) ----
__global__ __launch_bounds__(256)
void k2_stage3(const float* __restrict__ x, const float* __restrict__ w_sp_d,
               float* __restrict__ out) {
    __shared__ float s_s[ET][ET + 1];
    __shared__ float s_d[ET][ET + 1];
    __shared__ float s_c[ET][ET + 1];
    __shared__ float sw[9];
    const int b = blockIdx.z;
    const int ty0 = blockIdx.y * TS, tx0 = blockIdx.x * TS;
    const int tid = threadIdx.x;
    const float* dcd   = x + b * PLANE;
    const float* cd    = x + (Bb + b) * PLANE;
    const float* scs_o = out + (8 + b)  * PLANE;
    const float* cs_o  = out + (12 + b) * PLANE;

    if (tid == 0) {   // inline weight prep (spatial_d softplus-norm)
        float sd[9]; float sum = 0.f;
        for (int r = 0; r < 3; ++r)
            for (int c = 0; c < 3; ++c) {
                int cc = (c == 2) ? 0 : c;
                float v = log1pf(expf(w_sp_d[r * 2 + cc]));
                sd[r * 3 + c] = v; sum += v;
            }
        for (int k = 0; k < 9; ++k) sw[k] = sd[k] / sum;
    }

    for (int i = tid; i < ET * ET; i += 256) {
        int ly = i / ET, lx = i - ly * ET;
        int gy = ty0 - 1 + ly, gx = tx0 - 1 + lx;
        float sv = 0.f, vd = 0.f, vc = 0.f;
        if ((unsigned)gy < (unsigned)Hh && (unsigned)gx < (unsigned)Ww) {
            int idx = gy * Ww + gx;
            sv = scs_o[idx] * __builtin_amdgcn_rcpf(cs_o[idx] + EPSF);
            vd = dcd[idx];
            vc = cd[idx];
        }
        s_s[ly][lx] = sv; s_d[ly][lx] = vd; s_c[ly][lx] = vc;
    }
    __syncthreads();

    float wd[9];
    #pragma unroll
    for (int k = 0; k < 9; ++k) wd[k] = sw[k];

    for (int i = tid; i < TS * TS; i += 256) {
        int ly = i / TS, lx = i - ly * TS;
        int gy = ty0 + ly, gx = tx0 + lx;
        float sc = s_s[ly + 1][lx + 1];
        float nd = 0.f, nc = 0.f, den = 0.f;
        #pragma unroll
        for (int k = 0; k < 9; ++k) {
            float wsk = (k == 4) ? 1.f : (s_s[ly + k / 3][lx + k % 3] * sc);
            float w = wd[k] * wsk;
            nd  += w * s_d[ly + k / 3][lx + k % 3];
            nc  += w * s_c[ly + k / 3][lx + k % 3];
            den += w;
        }
        float rinv = __builtin_amdgcn_rcpf(den + EPSF);
        int idx = gy * Ww + gx;
        out[(2 * b)     * PLANE + idx] = nd * rinv;
        out[(2 * b + 1) * PLANE + idx] = nc * rinv;
    }
}

extern "C" void kernel_launch(void* const* d_in, const int* in_sizes, int n_in,
                              void* d_out, int out_size, void* d_ws, size_t ws_size,
                              hipStream_t stream) {
    const float* x        = (const float*)d_in[0];
    const float* scs      = (const float*)d_in[1];
    const float* cs       = (const float*)d_in[2];
    // d_in[3] = w_channel_d (1,1) -> normalizes to 1, unused
    const float* w_sp_d   = (const float*)d_in[4];
    const float* w_pow_s  = (const float*)d_in[5];
    const float* w_prop_s = (const float*)d_in[6];
    // d_in[7] = w_channel_s (1,1) -> normalizes to 1, unused
    const float* w_sp_s   = (const float*)d_in[8];
    float* out  = (float*)d_out;

    dim3 grid(Ww / TS, Hh / TS, Bb);   // 24 x 24 x 4
    k1_stage12<<<grid, 256, 0, stream>>>(x, scs, cs, w_sp_s, w_pow_s, w_prop_s, out);
    k2_stage3<<<grid, 256, 0, stream>>>(x, w_sp_d, out);
}